// Round 4
// baseline (1991.794 us; speedup 1.0000x reference)
//
#include <hip/hip_runtime.h>
#include <stdint.h>

// out[m,n] = -sqrt( sum_k (A[m,k] - B[n,k])^2 )
// A = features [M=16384, K=2048], B = prototypes [N=1000, K=2048].
// Diagnostic-robust build:
//  * OUTPUT WRITTEN AS FP32 (reference's literal output dtype).
//  * Input dtype (fp32 vs bf16) sniffed on-device, both supported.
//  * Direct sum-of-squared-differences: no norm pass, no workspace, no
//    __device__ globals, no MFMA/ext-vector/builtin constructs. One kernel.

#define KDIM 2048
#define TILE 64
#define BK 32

__global__ __launch_bounds__(256) void dist_kernel(
    const void* __restrict__ Araw,   // [M, K]
    const void* __restrict__ Braw,   // [N, K]
    float* __restrict__ out,         // [M, N] fp32
    int M, int N) {
  __shared__ float Af[TILE][BK + 1];
  __shared__ float Bf[TILE][BK + 1];

  const int tid = threadIdx.x;
  const int m0 = blockIdx.y * TILE;
  const int n0 = blockIdx.x * TILE;

  // Uniform dtype sniff: read first 64 uint16 words of A as bf16. Genuine
  // bf16 N(0,1) data -> max |x| < 10. fp32 data -> mantissa half-words give
  // |x| > 1e4 essentially surely. Same result in every block/lane.
  const uint16_t* sniff = (const uint16_t*)Araw;
  float mx = 0.f;
  for (int i = 0; i < 64; ++i) {
    float v = __uint_as_float(((uint32_t)sniff[i]) << 16);
    mx = fmaxf(mx, fabsf(v));
  }
  const bool isf32 = (mx > 1e4f);

  const float* A32 = (const float*)Araw;
  const float* B32 = (const float*)Braw;
  const uint16_t* A16 = (const uint16_t*)Araw;
  const uint16_t* B16 = (const uint16_t*)Braw;

  const int ty = tid >> 4;  // 0..15: m sub-block
  const int tx = tid & 15;  // 0..15: n sub-block

  float acc[4][4] = {};

  for (int k0 = 0; k0 < KDIM; k0 += BK) {
    // Stage 64x32 A- and B-tiles as fp32; 2048 elements each, 8 per thread.
#pragma unroll
    for (int i = 0; i < 8; ++i) {
      const int f = i * 256 + tid;
      const int r = f >> 5;   // 0..63
      const int c = f & 31;   // 0..31
      const size_t ka = (size_t)(m0 + r) * KDIM + (k0 + c);
      int rb = n0 + r;
      rb = rb < N ? rb : N - 1;  // clamp tail rows to a safe address
      const size_t kb = (size_t)rb * KDIM + (k0 + c);
      float av, bv;
      if (isf32) {
        av = A32[ka];
        bv = B32[kb];
      } else {
        av = __uint_as_float(((uint32_t)A16[ka]) << 16);
        bv = __uint_as_float(((uint32_t)B16[kb]) << 16);
      }
      Af[r][c] = av;
      Bf[r][c] = bv;
    }
    __syncthreads();

#pragma unroll 4
    for (int kk = 0; kk < BK; ++kk) {
      float a[4], b[4];
#pragma unroll
      for (int i = 0; i < 4; ++i) a[i] = Af[ty * 4 + i][kk];
#pragma unroll
      for (int j = 0; j < 4; ++j) b[j] = Bf[tx * 4 + j][kk];
#pragma unroll
      for (int i = 0; i < 4; ++i)
#pragma unroll
        for (int j = 0; j < 4; ++j) {
          const float d = a[i] - b[j];
          acc[i][j] = fmaf(d, d, acc[i][j]);
        }
    }
    __syncthreads();
  }

#pragma unroll
  for (int i = 0; i < 4; ++i) {
    const int m = m0 + ty * 4 + i;
#pragma unroll
    for (int j = 0; j < 4; ++j) {
      const int n = n0 + tx * 4 + j;
      if (m < M && n < N) out[(size_t)m * N + n] = -sqrtf(acc[i][j]);
    }
  }
}

extern "C" void kernel_launch(void* const* d_in, const int* in_sizes, int n_in,
                              void* d_out, int out_size, void* d_ws,
                              size_t ws_size, hipStream_t stream) {
  const void* feat = d_in[0];
  const void* prot = d_in[1];
  float* out = (float*)d_out;

  const int M = in_sizes[0] / KDIM;  // 16384 (element counts are dtype-free)
  const int N = in_sizes[1] / KDIM;  // 1000

  dim3 grid((N + TILE - 1) / TILE, (M + TILE - 1) / TILE);
  dist_kernel<<<grid, dim3(256), 0, stream>>>(feat, prot, out, M, N);
}